// Round 5
// baseline (87.121 us; speedup 1.0000x reference)
//
#include <hip/hip_runtime.h>
#include <hip/hip_bf16.h>
#include <stdint.h>
#include <stddef.h>

// Problem constants
#define B_    2
#define NREF  3
#define FDIM  256
#define HW    4096
#define DCLS  10
#define RTOT  12288          // NREF*HW reference pixels per batch
#define TT    128            // target pixels per block (4 waves)
#define RR    64             // reference pixels per chunk
#define RS    8              // r-axis split across blocks
#define RPB   1536           // RTOT/RS
#define NCH   24             // RPB/RR
#define NPIX  8192           // B_*HW
#define LOG2E 1.44269504f
#define C0    (-100.0f * LOG2E)   // exp(s-100) == exp2(s*log2e + C0)

typedef __attribute__((ext_vector_type(8))) short bf16x8;
typedef __attribute__((ext_vector_type(4))) float f32x4;
typedef __attribute__((ext_vector_type(4))) unsigned int u32x4;

__device__ __forceinline__ unsigned short f2bf(float x) {
  union { float f; unsigned u; } v; v.f = x;
  unsigned r = v.u + 0x7fffu + ((v.u >> 16) & 1u);   // RNE
  return (unsigned short)(r >> 16);
}
__device__ __forceinline__ unsigned pk2(float a, float b) {
  return (unsigned)f2bf(a) | ((unsigned)f2bf(b) << 16);
}
// single-instruction packed f32->bf16 (RNE), gfx950
__device__ __forceinline__ unsigned cvtpk(float a, float b) {
  unsigned r;
  asm("v_cvt_pk_bf16_f32 %0, %1, %2" : "=v"(r) : "v"(a), "v"(b));
  return r;
}
// async global->LDS, 16B per lane; LDS dest is wave-uniform base + lane*16
__device__ __forceinline__ void async16(const void* g, void* l) {
  __builtin_amdgcn_global_load_lds(
      (const __attribute__((address_space(1))) void*)g,
      (__attribute__((address_space(3))) void*)l, 16, 0, 0);
}
// one-hot pair: low/high 16-bit bf16 1.0 where label byte matches d=l15
__device__ __forceinline__ unsigned oh2(unsigned word, int l15) {
  return ((word & 255u) == (unsigned)l15 ? 0x3F80u : 0u) |
         (((word >> 8) & 255u) == (unsigned)l15 ? 0x3F800000u : 0u);
}

// ---------------- kernel 1: fused prep (transpose+convert) + label extract ----------------
__global__ __launch_bounds__(256) void k_pre(const float* __restrict__ ref,
                                             const float* __restrict__ tgt,
                                             const float* __restrict__ rl,
                                             char* __restrict__ outb,
                                             unsigned char* __restrict__ lab8) {
  const int tid = threadIdx.x;
  if (blockIdx.x < 256) {
    const int gid = blockIdx.x * 256 + tid;       // half-rows
    const int row = gid >> 1, half = gid & 1;     // row 0..32767
    const float* src;
    if (row < B_ * RTOT) {
      const int b = row / RTOT, rr2 = row % RTOT;
      src = ref + ((size_t)(b * NREF + (rr2 >> 12)) * FDIM) * HW + (rr2 & 4095);
    } else {
      const int r2 = row - B_ * RTOT;
      src = tgt + ((size_t)(r2 >> 12) * FDIM) * HW + (r2 & 4095);
    }
    char* dst = outb + (size_t)row * 512;
    const int sw = (row & 7) << 4;
    for (int ci = 0; ci < 16; ++ci) {
      const int c16 = half * 16 + ci;
      float v[8];
#pragma unroll
      for (int j = 0; j < 8; ++j) v[j] = src[(size_t)(c16 * 8 + j) * HW];
      u32x4 u;
      u[0] = pk2(v[0], v[1]); u[1] = pk2(v[2], v[3]);
      u[2] = pk2(v[4], v[5]); u[3] = pk2(v[6], v[7]);
      *(u32x4*)(dst + ((c16 * 16) ^ sw)) = u;
    }
  } else {
    const int idx = (blockIdx.x - 256) * 256 + tid;   // < 24576
    if (idx >= B_ * RTOT) return;
    const int b = idx / RTOT, r = idx % RTOT;
    const float* p = rl + ((size_t)((b * NREF + (r >> 12)) * DCLS)) * HW + (r & 4095);
    int v = 0;
#pragma unroll
    for (int d = 1; d < DCLS; ++d)
      if (p[(size_t)d * HW] > 0.5f) v = d;
    lab8[idx] = (unsigned char)v;
  }
}

// ---------------- kernel 2: fused QK-softmax-PV, software-pipelined ----------------
// grid = RS(8) * 32(tblocks) * B_(2) = 512 blocks of 256 threads, 2 blocks/CU.
// Pipeline: per step, QK(c+1) [MFMA+LDS pipes] is co-scheduled with exp/PV(c)
// [VALU pipe] — independent registers, same scheduling region, no barrier between.
__global__ __launch_bounds__(256, 2) void k_main(const char* __restrict__ refb,
                                                 const char* __restrict__ tgtb,
                                                 const unsigned char* __restrict__ lab8,
                                                 float* __restrict__ pred) {
  __shared__ __align__(16) char Ash[2][RR * 512];   // double-buffered ref chunk, 64 KB

  const int tid = threadIdx.x;
  const int lane = tid & 63;
  const int w = tid >> 6;                // wave 0..3
  const int l15 = lane & 15, l4 = lane >> 4;
  const int rh = w >> 1, th = w & 1;     // wave sub-tile: 32r x 64t
  const int swz = (l15 & 7) << 4;

  const int bid = blockIdx.x;
  const int rs = bid & 7;
  const int tb = (bid >> 3) & 31;
  const int b  = bid >> 8;

  // ---- B fragments in registers: wave's 64 t x full K=256 (128 VGPR) ----
  bf16x8 bfr[4][8];
  {
    const char* base = tgtb + ((size_t)(b * HW + tb * TT + th * 64)) * 512;
#pragma unroll
    for (int nt = 0; nt < 4; ++nt) {
      const char* rp = base + (size_t)((nt * 16 + l15) * 512);
#pragma unroll
      for (int ks = 0; ks < 8; ++ks)
        bfr[nt][ks] = *(const bf16x8*)(rp + ((ks * 64 + l4 * 16) ^ swz));
    }
  }

  f32x4 pacc[4];
#pragma unroll
  for (int i = 0; i < 4; ++i) pacc[i] = f32x4{0.f, 0.f, 0.f, 0.f};

  const char* Asrc = refb + ((size_t)(b * RTOT + rs * RPB)) * 512;
  const unsigned char* lb = lab8 + b * RTOT + rs * RPB;

  // stage chunk c into buf[c&1]
  auto stage = [&](int c) {
    const char* s = Asrc + (size_t)c * (RR * 512);
    char* d = &Ash[c & 1][0];
#pragma unroll
    for (int i = 0; i < 8; ++i) {
      const int seg = i * 4 + w;
      async16(s + seg * 1024 + lane * 16, d + seg * 1024);
    }
  };
  // QK^T of one chunk: 64 MFMA/wave; A from LDS (swizzled), B from regs
  auto qk = [&](f32x4 (&acc)[2][4], const char* ab) {
#pragma unroll
    for (int i = 0; i < 2; ++i)
#pragma unroll
      for (int j = 0; j < 4; ++j) acc[i][j] = f32x4{0.f, 0.f, 0.f, 0.f};
#pragma unroll
    for (int ks = 0; ks < 8; ++ks) {
      bf16x8 af[2];
#pragma unroll
      for (int mt = 0; mt < 2; ++mt)
        af[mt] = *(const bf16x8*)(ab + (rh * 32 + mt * 16 + l15) * 512 +
                                  ((ks * 64 + l4 * 16) ^ swz));
#pragma unroll
      for (int mt = 0; mt < 2; ++mt)
#pragma unroll
        for (int nt = 0; nt < 4; ++nt)
          acc[mt][nt] = __builtin_amdgcn_mfma_f32_16x16x32_bf16(
              af[mt], bfr[nt][ks], acc[mt][nt], 0, 0, 0);
    }
  };
  // exp + pack + PV of one chunk's accumulator (all wave-local, pure VALU+MFMA)
  auto pv = [&](const f32x4 (&acc)[2][4], unsigned la, unsigned lb2) {
    union { bf16x8 v; unsigned u[4]; } lf;
    lf.u[0] = oh2(la, l15);        lf.u[1] = oh2(la >> 16, l15);
    lf.u[2] = oh2(lb2, l15);       lf.u[3] = oh2(lb2 >> 16, l15);
#pragma unroll
    for (int nt = 0; nt < 4; ++nt) {
      const f32x4 a0 = acc[0][nt], a1 = acc[1][nt];
      float p0 = __builtin_amdgcn_exp2f(__builtin_fmaf(a0[0], LOG2E, C0));
      float p1 = __builtin_amdgcn_exp2f(__builtin_fmaf(a0[1], LOG2E, C0));
      float p2 = __builtin_amdgcn_exp2f(__builtin_fmaf(a0[2], LOG2E, C0));
      float p3 = __builtin_amdgcn_exp2f(__builtin_fmaf(a0[3], LOG2E, C0));
      float p4 = __builtin_amdgcn_exp2f(__builtin_fmaf(a1[0], LOG2E, C0));
      float p5 = __builtin_amdgcn_exp2f(__builtin_fmaf(a1[1], LOG2E, C0));
      float p6 = __builtin_amdgcn_exp2f(__builtin_fmaf(a1[2], LOG2E, C0));
      float p7 = __builtin_amdgcn_exp2f(__builtin_fmaf(a1[3], LOG2E, C0));
      union { bf16x8 v; unsigned u[4]; } pf;
      pf.u[0] = cvtpk(p0, p1); pf.u[1] = cvtpk(p2, p3);
      pf.u[2] = cvtpk(p4, p5); pf.u[3] = cvtpk(p6, p7);
      pacc[nt] = __builtin_amdgcn_mfma_f32_16x16x32_bf16(lf.v, pf.v, pacc[nt], 0, 0, 0);
    }
  };

  f32x4 accA[2][4], accB[2][4];

  // prologue: stage(0); drain; stage(1); QK(0)->accA
  stage(0);
  __syncthreads();
  stage(1);
  qk(accA, &Ash[0][0]);

  // steady state: 11 double-steps covering STEP(0)..STEP(21)
#pragma unroll 1
  for (int c = 0; c < 22; c += 2) {
    {   // STEP(c) even: PV(c) from accA; QK(c+1)->accB (buf1); stage(c+2)->buf0
      const unsigned la  = *(const unsigned*)(lb + c * RR + rh * 32 + l4 * 4);
      const unsigned l2_ = *(const unsigned*)(lb + c * RR + rh * 32 + 16 + l4 * 4);
      __syncthreads();          // drain DMA(c+1); all QK(c) readers of buf0 done
      stage(c + 2);
      qk(accB, &Ash[1][0]);
      pv(accA, la, l2_);
    }
    {   // STEP(c+1) odd: PV(c+1) from accB; QK(c+2)->accA (buf0); stage(c+3)->buf1
      const int c1 = c + 1;
      const unsigned la  = *(const unsigned*)(lb + c1 * RR + rh * 32 + l4 * 4);
      const unsigned l2_ = *(const unsigned*)(lb + c1 * RR + rh * 32 + 16 + l4 * 4);
      __syncthreads();          // drain DMA(c+2); all QK(c+1) readers of buf1 done
      stage(c1 + 2);
      qk(accA, &Ash[0][0]);
      pv(accB, la, l2_);
    }
  }
  {   // STEP(22): PV(22) from accA; QK(23)->accB (buf1); no stage
    const unsigned la  = *(const unsigned*)(lb + 22 * RR + rh * 32 + l4 * 4);
    const unsigned l2_ = *(const unsigned*)(lb + 22 * RR + rh * 32 + 16 + l4 * 4);
    __syncthreads();            // drain DMA(23)
    qk(accB, &Ash[1][0]);
    pv(accA, la, l2_);
  }
  {   // tail: PV(23) from accB (registers only)
    const unsigned la  = *(const unsigned*)(lb + 23 * RR + rh * 32 + l4 * 4);
    const unsigned l2_ = *(const unsigned*)(lb + 23 * RR + rh * 32 + 16 + l4 * 4);
    pv(accB, la, l2_);
  }

  // ---- cross-wave reduction of rh partials (once), then global write ----
  __syncthreads();                       // everyone done with Ash (no DMA pending)
  float* sc = (float*)&Ash[0][0];        // 8 KB scratch
  if (rh == 1) {
#pragma unroll
    for (int nt = 0; nt < 4; ++nt)
      *(f32x4*)&sc[((th * 64 + lane) * 4 + nt) * 4] = pacc[nt];
  }
  __syncthreads();
  if (rh == 0) {
#pragma unroll
    for (int nt = 0; nt < 4; ++nt) {
      pacc[nt] += *(const f32x4*)&sc[((th * 64 + lane) * 4 + nt) * 4];
      const int t = th * 64 + nt * 16 + l15;
      const size_t o = (((size_t)(rs * B_ + b)) * HW + (size_t)tb * TT + t) * 16 + l4 * 4;
      *(f32x4*)&pred[o] = pacc[nt];
    }
  }
}

// ---------------- kernel 3: per-pixel loss terms + block reduce ----------------
__global__ __launch_bounds__(256) void k_epi(const float* __restrict__ pred,
                                             const int* __restrict__ tl,
                                             float* __restrict__ red) {
  const int idx = blockIdx.x * 256 + threadIdx.x;   // < 8192
  const int b = idx >> 12, t = idx & 4095;
  union { f32x4 v[3]; float f[12]; } S;
  S.v[0] = f32x4{0.f, 0.f, 0.f, 0.f};
  S.v[1] = f32x4{0.f, 0.f, 0.f, 0.f};
  S.v[2] = f32x4{0.f, 0.f, 0.f, 0.f};
#pragma unroll
  for (int r = 0; r < RS; ++r) {
    const f32x4* p = (const f32x4*)&pred[(((size_t)(r * B_ + b)) * HW + t) * 16];
    S.v[0] += p[0]; S.v[1] += p[1]; S.v[2] += p[2];
  }
  float T = 0.f;
#pragma unroll
  for (int d = 0; d < DCLS; ++d) T += S.f[d];
  const float inv = 1.f / T;
  const int lb = tl[idx];
  float se = 0.f, zt = 0.f;
#pragma unroll
  for (int d = 0; d < DCLS; ++d) {
    const float z = S.f[d] * inv;      // pred prob in [0,1]
    se += __expf(z);
    if (d == lb) zt = z;
  }
  const float logpt = zt - __logf(se);
  const float pt = __expf(zt) / se;
  const float focal = sqrtf(fmaxf(1.f - pt, 0.f));   // gamma = 0.5

  float lp = logpt, fo = focal;
#pragma unroll
  for (int off = 32; off; off >>= 1) {
    lp += __shfl_down(lp, off);
    fo += __shfl_down(fo, off);
  }
  __shared__ float rb_[8];
  const int lane = threadIdx.x & 63, wv = threadIdx.x >> 6;
  if (lane == 0) { rb_[wv] = lp; rb_[4 + wv] = fo; }
  __syncthreads();
  if (threadIdx.x == 0) {
    red[blockIdx.x * 2 + 0] = rb_[0] + rb_[1] + rb_[2] + rb_[3];
    red[blockIdx.x * 2 + 1] = rb_[4] + rb_[5] + rb_[6] + rb_[7];
  }
}

// ---------------- kernel 4: final scalar ----------------
__global__ void k_fin(const float* __restrict__ red, float* __restrict__ out) {
  const int tid = threadIdx.x;   // 64
  float lp = 0.f, fo = 0.f;
  if (tid < 32) { lp = red[tid * 2]; fo = red[tid * 2 + 1]; }
#pragma unroll
  for (int off = 16; off; off >>= 1) {
    lp += __shfl_down(lp, off);
    fo += __shfl_down(fo, off);
  }
  if (tid == 0) {
    const float ce = -lp / (float)NPIX;       // ce = -mean(log_pt)
    out[0] = ce * (fo / (float)NPIX);         // loss = ce * mean(focal)
  }
}

extern "C" void kernel_launch(void* const* d_in, const int* in_sizes, int n_in,
                              void* d_out, int out_size, void* d_ws, size_t ws_size,
                              hipStream_t stream)
{
  const float* ref  = (const float*)d_in[0];
  const float* tgt  = (const float*)d_in[1];
  const float* rl   = (const float*)d_in[2];
  const int*   tlab = (const int*)d_in[3];
  float* out = (float*)d_out;

  char* ws = (char*)d_ws;
  char* refb = ws;                                    // 32768 rows * 512 B = 16 MB (ref + tgt)
  char* tgtb = ws + (size_t)24576 * 512;              // tgt rows start at 24576
  unsigned char* lab8 = (unsigned char*)(ws + 16777216);          // 24 KB (pad 32 KB)
  float* pred = (float*)(ws + 16777216 + 32768);                  // 4 MB (RS*B*HW*16 f32)
  float* red  = (float*)(ws + 16777216 + 32768 + 4194304);        // 256 B

  k_pre<<<352, 256, 0, stream>>>(ref, tgt, rl, refb, lab8);
  k_main<<<512, 256, 0, stream>>>(refb, tgtb, lab8, pred);
  k_epi<<<32, 256, 0, stream>>>(pred, tlab, red);
  k_fin<<<1, 64, 0, stream>>>(red, out);
}

// Round 6
// 80.369 us; speedup vs baseline: 1.0840x; 1.0840x over previous
//
#include <hip/hip_runtime.h>
#include <hip/hip_bf16.h>
#include <stdint.h>
#include <stddef.h>

// Problem constants
#define B_    2
#define NREF  3
#define FDIM  256
#define HW    4096
#define DCLS  10
#define RTOT  12288          // NREF*HW reference pixels per batch
#define TT    128            // target pixels per block (4 waves)
#define RR    64             // reference pixels per chunk
#define RS    8              // r-axis split across blocks
#define RPB   1536           // RTOT/RS
#define NCH   24             // RPB/RR
#define NPIX  8192           // B_*HW
#define LOG2E 1.44269504f
#define C0    (-100.0f * LOG2E)   // exp(s-100) == exp2(s*log2e + C0)

typedef __attribute__((ext_vector_type(8))) short bf16x8;
typedef __attribute__((ext_vector_type(4))) float f32x4;
typedef __attribute__((ext_vector_type(4))) unsigned int u32x4;

__device__ __forceinline__ unsigned short f2bf(float x) {
  union { float f; unsigned u; } v; v.f = x;
  unsigned r = v.u + 0x7fffu + ((v.u >> 16) & 1u);   // RNE
  return (unsigned short)(r >> 16);
}
__device__ __forceinline__ unsigned pk2(float a, float b) {
  return (unsigned)f2bf(a) | ((unsigned)f2bf(b) << 16);
}
// single-instruction packed f32->bf16 (RNE), gfx950
__device__ __forceinline__ unsigned cvtpk(float a, float b) {
  unsigned r;
  asm("v_cvt_pk_bf16_f32 %0, %1, %2" : "=v"(r) : "v"(a), "v"(b));
  return r;
}
// async global->LDS, 16B per lane; LDS dest is wave-uniform base + lane*16
__device__ __forceinline__ void async16(const void* g, void* l) {
  __builtin_amdgcn_global_load_lds(
      (const __attribute__((address_space(1))) void*)g,
      (__attribute__((address_space(3))) void*)l, 16, 0, 0);
}
// one-hot pair: low/high 16-bit bf16 1.0 where label byte matches d=l15
__device__ __forceinline__ unsigned oh2(unsigned word, int l15) {
  return ((word & 255u) == (unsigned)l15 ? 0x3F80u : 0u) |
         (((word >> 8) & 255u) == (unsigned)l15 ? 0x3F800000u : 0u);
}

// ---------------- kernel 1: fused prep (transpose+convert) + label extract ----------------
// blocks [0,256): ref/tgt -> bf16 rows of 512B with XOR swizzle baked per row.
// row = bid*128 + (tid&127): a wave's 64 lanes read 64 consecutive hw pixels
// -> 256B contiguous per global load instruction (fully coalesced).
__global__ __launch_bounds__(256) void k_pre(const float* __restrict__ ref,
                                             const float* __restrict__ tgt,
                                             const float* __restrict__ rl,
                                             char* __restrict__ outb,
                                             unsigned char* __restrict__ lab8) {
  const int tid = threadIdx.x;
  if (blockIdx.x < 256) {
    const int row = blockIdx.x * 128 + (tid & 127);   // row 0..32767
    const int half = tid >> 7;
    const float* src;
    if (row < B_ * RTOT) {
      const int b = row / RTOT, rr2 = row % RTOT;
      src = ref + ((size_t)(b * NREF + (rr2 >> 12)) * FDIM) * HW + (rr2 & 4095);
    } else {
      const int r2 = row - B_ * RTOT;
      src = tgt + ((size_t)(r2 >> 12) * FDIM) * HW + (r2 & 4095);
    }
    char* dst = outb + (size_t)row * 512;
    const int sw = (row & 7) << 4;
    for (int ci = 0; ci < 16; ++ci) {
      const int c16 = half * 16 + ci;
      float v[8];
#pragma unroll
      for (int j = 0; j < 8; ++j) v[j] = src[(size_t)(c16 * 8 + j) * HW];
      u32x4 u;
      u[0] = pk2(v[0], v[1]); u[1] = pk2(v[2], v[3]);
      u[2] = pk2(v[4], v[5]); u[3] = pk2(v[6], v[7]);
      *(u32x4*)(dst + ((c16 * 16) ^ sw)) = u;
    }
  } else {
    const int idx = (blockIdx.x - 256) * 256 + tid;   // < 24576
    if (idx >= B_ * RTOT) return;
    const int b = idx / RTOT, r = idx % RTOT;
    const float* p = rl + ((size_t)((b * NREF + (r >> 12)) * DCLS)) * HW + (r & 4095);
    int v = 0;
#pragma unroll
    for (int d = 1; d < DCLS; ++d)
      if (p[(size_t)d * HW] > 0.5f) v = d;
    lab8[idx] = (unsigned char)v;
  }
}

// ---------------- kernel 2: fused QK-softmax-PV ----------------
// grid = RS(8) * 32(tblocks) * B_(2) = 512 blocks of 256 threads, 2 blocks/CU.
// bid&7 == rs == XCD id -> all t-blocks sharing an A-slice stay on one XCD.
// Single accumulator set (round-5 double-acc spilled); manual even/odd chunk
// unroll so LDS buffer bases are compile-time immediates; A-read addresses
// fully precomputed: addr = ap[mt][ks&1] + BUFOFS + (ks>>1)*128.
__global__ __launch_bounds__(256, 2) void k_main(const char* __restrict__ refb,
                                                 const char* __restrict__ tgtb,
                                                 const unsigned char* __restrict__ lab8,
                                                 float* __restrict__ pred) {
  __shared__ __align__(16) char Ash[2][RR * 512];   // double-buffered ref chunk, 64 KB

  const int tid = threadIdx.x;
  const int lane = tid & 63;
  const int w = tid >> 6;                // wave 0..3
  const int l15 = lane & 15, l4 = lane >> 4;
  const int rh = w >> 1, th = w & 1;     // wave sub-tile: 32r x 64t
  const int swz = (l15 & 7) << 4;

  const int bid = blockIdx.x;
  const int rs = bid & 7;
  const int tb = (bid >> 3) & 31;
  const int b  = bid >> 8;

  // ---- B fragments in registers: wave's 64 t x full K=256 (128 VGPR) ----
  bf16x8 bfr[4][8];
  {
    const char* base = tgtb + ((size_t)(b * HW + tb * TT + th * 64)) * 512;
#pragma unroll
    for (int nt = 0; nt < 4; ++nt) {
      const char* rp = base + (size_t)((nt * 16 + l15) * 512);
#pragma unroll
      for (int ks = 0; ks < 8; ++ks)
        bfr[nt][ks] = *(const bf16x8*)(rp + ((ks * 64 + l4 * 16) ^ swz));
    }
  }

  f32x4 pacc[4];
#pragma unroll
  for (int i = 0; i < 4; ++i) pacc[i] = f32x4{0.f, 0.f, 0.f, 0.f};

  const char* Asrc = refb + ((size_t)(b * RTOT + rs * RPB)) * 512;

  // precomputed A-read base pointers (buf0); buf1 reached via +32768 immediate
  const char* ap00 = &Ash[0][(rh * 32 +  0 + l15) * 512 + ((     l4 * 16) ^ swz)];
  const char* ap01 = &Ash[0][(rh * 32 +  0 + l15) * 512 + ((64 + l4 * 16) ^ swz)];
  const char* ap10 = &Ash[0][(rh * 32 + 16 + l15) * 512 + ((     l4 * 16) ^ swz)];
  const char* ap11 = &Ash[0][(rh * 32 + 16 + l15) * 512 + ((64 + l4 * 16) ^ swz)];

  // stage chunk at src -> dbuf (32 segs of 1 KB, 8 per wave)
  auto stage = [&](const char* s, char* dbuf) {
#pragma unroll
    for (int i2 = 0; i2 < 8; ++i2) {
      const int seg = i2 * 4 + w;
      async16(s + seg * 1024 + lane * 16, dbuf + seg * 1024);
    }
  };
  // QK^T of one chunk: 64 MFMA/wave; A via precomputed addrs + immediates
  auto qk = [&](f32x4 (&acc)[2][4], const int OFS) {
#pragma unroll
    for (int i2 = 0; i2 < 2; ++i2)
#pragma unroll
      for (int j = 0; j < 4; ++j) acc[i2][j] = f32x4{0.f, 0.f, 0.f, 0.f};
    __builtin_amdgcn_s_setprio(1);
#pragma unroll
    for (int ks = 0; ks < 8; ++ks) {
      const int ko = OFS + (ks >> 1) * 128;
      const bf16x8 af0 = *(const bf16x8*)(((ks & 1) ? ap01 : ap00) + ko);
      const bf16x8 af1 = *(const bf16x8*)(((ks & 1) ? ap11 : ap10) + ko);
#pragma unroll
      for (int nt = 0; nt < 4; ++nt)
        acc[0][nt] = __builtin_amdgcn_mfma_f32_16x16x32_bf16(
            af0, bfr[nt][ks], acc[0][nt], 0, 0, 0);
#pragma unroll
      for (int nt = 0; nt < 4; ++nt)
        acc[1][nt] = __builtin_amdgcn_mfma_f32_16x16x32_bf16(
            af1, bfr[nt][ks], acc[1][nt], 0, 0, 0);
    }
    __builtin_amdgcn_s_setprio(0);
  };
  // exp + pack + PV (wave-local; acc reg layout IS the PV B-frag layout)
  auto pv = [&](const f32x4 (&acc)[2][4], unsigned la, unsigned lb2) {
    union { bf16x8 v; unsigned u[4]; } lf;
    lf.u[0] = oh2(la, l15);        lf.u[1] = oh2(la >> 16, l15);
    lf.u[2] = oh2(lb2, l15);       lf.u[3] = oh2(lb2 >> 16, l15);
#pragma unroll
    for (int nt = 0; nt < 4; ++nt) {
      const f32x4 a0 = acc[0][nt], a1 = acc[1][nt];
      float p0 = __builtin_amdgcn_exp2f(__builtin_fmaf(a0[0], LOG2E, C0));
      float p1 = __builtin_amdgcn_exp2f(__builtin_fmaf(a0[1], LOG2E, C0));
      float p2 = __builtin_amdgcn_exp2f(__builtin_fmaf(a0[2], LOG2E, C0));
      float p3 = __builtin_amdgcn_exp2f(__builtin_fmaf(a0[3], LOG2E, C0));
      float p4 = __builtin_amdgcn_exp2f(__builtin_fmaf(a1[0], LOG2E, C0));
      float p5 = __builtin_amdgcn_exp2f(__builtin_fmaf(a1[1], LOG2E, C0));
      float p6 = __builtin_amdgcn_exp2f(__builtin_fmaf(a1[2], LOG2E, C0));
      float p7 = __builtin_amdgcn_exp2f(__builtin_fmaf(a1[3], LOG2E, C0));
      union { bf16x8 v; unsigned u[4]; } pf;
      pf.u[0] = cvtpk(p0, p1); pf.u[1] = cvtpk(p2, p3);
      pf.u[2] = cvtpk(p4, p5); pf.u[3] = cvtpk(p6, p7);
      pacc[nt] = __builtin_amdgcn_mfma_f32_16x16x32_bf16(lf.v, pf.v, pacc[nt], 0, 0, 0);
    }
  };

  f32x4 acc[2][4];
  const unsigned char* lbp = lab8 + b * RTOT + rs * RPB + rh * 32 + l4 * 4;
  const char* Acur = Asrc + RR * 512;    // global source of the NEXT chunk

  stage(Asrc, &Ash[0][0]);               // prologue: chunk 0 -> buf0

#pragma unroll 1
  for (int i = 0; i < 11; ++i) {
    {   // even chunk (buf0): stage next -> buf1
      const unsigned la  = *(const unsigned*)lbp;
      const unsigned l2_ = *(const unsigned*)(lbp + 16);
      __syncthreads();                   // drain DMA(cur); readers of buf1 done
      stage(Acur, &Ash[1][0]); Acur += RR * 512;
      qk(acc, 0);
      pv(acc, la, l2_);
      lbp += RR;
    }
    {   // odd chunk (buf1): stage next -> buf0
      const unsigned la  = *(const unsigned*)lbp;
      const unsigned l2_ = *(const unsigned*)(lbp + 16);
      __syncthreads();
      stage(Acur, &Ash[0][0]); Acur += RR * 512;
      qk(acc, 32768);
      pv(acc, la, l2_);
      lbp += RR;
    }
  }
  {   // chunk 22 (even, buf0): stage 23 -> buf1
    const unsigned la  = *(const unsigned*)lbp;
    const unsigned l2_ = *(const unsigned*)(lbp + 16);
    __syncthreads();
    stage(Acur, &Ash[1][0]);
    qk(acc, 0);
    pv(acc, la, l2_);
    lbp += RR;
  }
  {   // chunk 23 (odd, buf1): no stage
    const unsigned la  = *(const unsigned*)lbp;
    const unsigned l2_ = *(const unsigned*)(lbp + 16);
    __syncthreads();
    qk(acc, 32768);
    pv(acc, la, l2_);
  }

  // ---- cross-wave reduction of rh partials (once), then global write ----
  __syncthreads();                       // everyone done with Ash (no DMA pending)
  float* sc = (float*)&Ash[0][0];        // 8 KB scratch
  if (rh == 1) {
#pragma unroll
    for (int nt = 0; nt < 4; ++nt)
      *(f32x4*)&sc[((th * 64 + lane) * 4 + nt) * 4] = pacc[nt];
  }
  __syncthreads();
  if (rh == 0) {
#pragma unroll
    for (int nt = 0; nt < 4; ++nt) {
      pacc[nt] += *(const f32x4*)&sc[((th * 64 + lane) * 4 + nt) * 4];
      const int t = th * 64 + nt * 16 + l15;
      const size_t o = (((size_t)(rs * B_ + b)) * HW + (size_t)tb * TT + t) * 16 + l4 * 4;
      *(f32x4*)&pred[o] = pacc[nt];
    }
  }
}

// ---------------- kernel 3: per-pixel loss terms + block reduce ----------------
__global__ __launch_bounds__(256) void k_epi(const float* __restrict__ pred,
                                             const int* __restrict__ tl,
                                             float* __restrict__ red) {
  const int idx = blockIdx.x * 256 + threadIdx.x;   // < 8192
  const int b = idx >> 12, t = idx & 4095;
  union { f32x4 v[3]; float f[12]; } S;
  S.v[0] = f32x4{0.f, 0.f, 0.f, 0.f};
  S.v[1] = f32x4{0.f, 0.f, 0.f, 0.f};
  S.v[2] = f32x4{0.f, 0.f, 0.f, 0.f};
#pragma unroll
  for (int r = 0; r < RS; ++r) {
    const f32x4* p = (const f32x4*)&pred[(((size_t)(r * B_ + b)) * HW + t) * 16];
    S.v[0] += p[0]; S.v[1] += p[1]; S.v[2] += p[2];
  }
  float T = 0.f;
#pragma unroll
  for (int d = 0; d < DCLS; ++d) T += S.f[d];
  const float inv = 1.f / T;
  const int lb = tl[idx];
  float se = 0.f, zt = 0.f;
#pragma unroll
  for (int d = 0; d < DCLS; ++d) {
    const float z = S.f[d] * inv;      // pred prob in [0,1]
    se += __expf(z);
    if (d == lb) zt = z;
  }
  const float logpt = zt - __logf(se);
  const float pt = __expf(zt) / se;
  const float focal = sqrtf(fmaxf(1.f - pt, 0.f));   // gamma = 0.5

  float lp = logpt, fo = focal;
#pragma unroll
  for (int off = 32; off; off >>= 1) {
    lp += __shfl_down(lp, off);
    fo += __shfl_down(fo, off);
  }
  __shared__ float rb_[8];
  const int lane = threadIdx.x & 63, wv = threadIdx.x >> 6;
  if (lane == 0) { rb_[wv] = lp; rb_[4 + wv] = fo; }
  __syncthreads();
  if (threadIdx.x == 0) {
    red[blockIdx.x * 2 + 0] = rb_[0] + rb_[1] + rb_[2] + rb_[3];
    red[blockIdx.x * 2 + 1] = rb_[4] + rb_[5] + rb_[6] + rb_[7];
  }
}

// ---------------- kernel 4: final scalar ----------------
__global__ void k_fin(const float* __restrict__ red, float* __restrict__ out) {
  const int tid = threadIdx.x;   // 64
  float lp = 0.f, fo = 0.f;
  if (tid < 32) { lp = red[tid * 2]; fo = red[tid * 2 + 1]; }
#pragma unroll
  for (int off = 16; off; off >>= 1) {
    lp += __shfl_down(lp, off);
    fo += __shfl_down(fo, off);
  }
  if (tid == 0) {
    const float ce = -lp / (float)NPIX;       // ce = -mean(log_pt)
    out[0] = ce * (fo / (float)NPIX);         // loss = ce * mean(focal)
  }
}

extern "C" void kernel_launch(void* const* d_in, const int* in_sizes, int n_in,
                              void* d_out, int out_size, void* d_ws, size_t ws_size,
                              hipStream_t stream)
{
  const float* ref  = (const float*)d_in[0];
  const float* tgt  = (const float*)d_in[1];
  const float* rl   = (const float*)d_in[2];
  const int*   tlab = (const int*)d_in[3];
  float* out = (float*)d_out;

  char* ws = (char*)d_ws;
  char* refb = ws;                                    // 32768 rows * 512 B = 16 MB (ref + tgt)
  char* tgtb = ws + (size_t)24576 * 512;              // tgt rows start at 24576
  unsigned char* lab8 = (unsigned char*)(ws + 16777216);          // 24 KB (pad 32 KB)
  float* pred = (float*)(ws + 16777216 + 32768);                  // 4 MB (RS*B*HW*16 f32)
  float* red  = (float*)(ws + 16777216 + 32768 + 4194304);        // 256 B

  k_pre<<<352, 256, 0, stream>>>(ref, tgt, rl, refb, lab8);
  k_main<<<512, 256, 0, stream>>>(refb, tgtb, lab8, pred);
  k_epi<<<32, 256, 0, stream>>>(pred, tlab, red);
  k_fin<<<1, 64, 0, stream>>>(red, out);
}